// Round 4
// baseline (240.596 us; speedup 1.0000x reference)
//
#include <hip/hip_runtime.h>
#include <hip/hip_bf16.h>

// Problem constants: N=50000, K=32, D=128.
#define D     128
#define TWO_D 256
#define KNB   32

typedef __attribute__((ext_vector_type(8))) short    s8;   // 8 x 16-bit (4 VGPR)
typedef __attribute__((ext_vector_type(8))) _Float16 h8;   // mfma operand view
typedef __attribute__((ext_vector_type(2))) _Float16 h2v;
typedef __attribute__((ext_vector_type(4))) float    f4;   // MFMA acc

__device__ inline unsigned short f2h(float f) {
    return __builtin_bit_cast(unsigned short, (_Float16)f);
}
__device__ inline float h2f(unsigned short u) {
    return (float)__builtin_bit_cast(_Float16, u);
}

union v16u { s8 s; h2v h[4]; };

// 8-elem fp16 dot with f32 accumulate; v_dot2_f32_f16 when available.
__device__ inline float dot8(s8 x, s8 w, float acc) {
#if __has_builtin(__builtin_amdgcn_fdot2)
    v16u ux, uw; ux.s = x; uw.s = w;
#pragma unroll
    for (int j = 0; j < 4; ++j)
        acc = __builtin_amdgcn_fdot2(ux.h[j], uw.h[j], acc, false);
#else
#pragma unroll
    for (int j = 0; j < 8; ++j)
        acc = fmaf(h2f((unsigned short)x[j]), h2f((unsigned short)w[j]), acc);
#endif
    return acc;
}

// Direct global->LDS DMA, 16 B per lane. LDS dest = base + lane*16 (linear);
// global src is per-lane. Zero VGPR destination cost; tracked by vmcnt.
__device__ inline void gl_lds16(const void* g, void* l) {
    __builtin_amdgcn_global_load_lds(
        (const __attribute__((address_space(1))) void*)g,
        (__attribute__((address_space(3))) void*)l, 16, 0, 0);
}

__device__ inline s8 pack8(float4 x, float4 y) {
    s8 q;
    q[0]=(short)f2h(x.x); q[1]=(short)f2h(x.y); q[2]=(short)f2h(x.z); q[3]=(short)f2h(x.w);
    q[4]=(short)f2h(y.x); q[5]=(short)f2h(y.y); q[6]=(short)f2h(y.z); q[7]=(short)f2h(y.w);
    return q;
}

// ---------------------------------------------------------------------------
// Cast kernel: v_fea, t_emb (f32) -> packed ph[n][0:128]=v, [128:256]=t (fp16).
// One contiguous 512B row per node => each edge gather is a single 512B block.
// ---------------------------------------------------------------------------
__global__ __launch_bounds__(256) void cast_kernel(
    const float* __restrict__ a, const float* __restrict__ b,
    unsigned short* __restrict__ ph, int total)   // total = M*16
{
    int i = blockIdx.x * 256 + threadIdx.x;
    if (i >= total) return;
    int n = i >> 4, j = i & 15;
    const float4* pv = (const float4*)(a + (size_t)n * D + j * 8);
    const float4* pt = (const float4*)(b + (size_t)n * D + j * 8);
    float4 v0 = pv[0], v1 = pv[1];
    float4 t0 = pt[0], t1 = pt[1];
    *(s8*)(ph + (size_t)n * TWO_D + j * 8)     = pack8(v0, v1);
    *(s8*)(ph + (size_t)n * TWO_D + D + j * 8) = pack8(t0, t1);
}

// ---------------------------------------------------------------------------
// Kernel A: wq = ph @ W^T, one-shot full-LDS GEMM. K=256 staged entirely in
// LDS (two 128-col halves), 2 barriers total per block.
//   As/Bs[half][row][256B]; col-byte XOR-swizzle ((row&7)<<4) kills the
//   stride-256B bank conflict on ds_read_b128 frag reads (G4). A staged via
//   global_load_lds with PRE-SWIZZLED global source (m173 pattern); B (W,
//   f32, L2-hot) through regs with inline cvt + swizzled ds_write.
//   Pipeline: stageA0+B0 | sync | stageA1(DMA)+loadB1 | MFMA h0 | writeB1 |
//   sync | MFMA h1 | epilogue.  1 block/CU (128 KiB LDS).
// ---------------------------------------------------------------------------
#define BM 128
#define BN 128

__global__ __launch_bounds__(256) void gemm_wq_mfma(
    const unsigned short* __restrict__ ph, const float* __restrict__ W,
    unsigned short* __restrict__ wq_h, int M)
{
    __shared__ char As[2][128 * 256];
    __shared__ char Bs[2][128 * 256];

    const int tid  = threadIdx.x;
    const int w    = tid >> 6;
    const int lane = tid & 63;
    const int quad = lane >> 4;
    const int l16  = lane & 15;
    const int row0 = blockIdx.x * BM;
    const int i0   = blockIdx.y * BN;

    const int srow_off = tid >> 4;          // 0..15: row within a 16-row round
    const int scol     = (tid & 15) * 16;   // byte col within 256B half-row

    f4 acc[2][8] = {};

    auto A_dma = [&](int h) {
#pragma unroll
        for (int r = 0; r < 8; ++r) {
            int row = r * 16 + srow_off;
            int arow = row0 + row; if (arow >= M) arow = M - 1;   // clamp
            gl_lds16((const char*)ph + (size_t)arow * 512 + h * 256
                         + (scol ^ ((row & 7) << 4)),             // pre-swizzled src
                     As[h] + r * 4096 + w * 1024);
        }
    };
    auto compute_half = [&](int h) {
#pragma unroll
        for (int kk = 0; kk < 4; ++kk) {
            int cb = kk * 64 + quad * 16;
            int ra0 = w * 32 + l16, ra1 = ra0 + 16;
            s8 af0 = *(const s8*)(As[h] + ra0 * 256 + (cb ^ ((ra0 & 7) << 4)));
            s8 af1 = *(const s8*)(As[h] + ra1 * 256 + (cb ^ ((ra1 & 7) << 4)));
#pragma unroll
            for (int nt = 0; nt < 8; ++nt) {
                int rb = nt * 16 + l16;
                s8 bf = *(const s8*)(Bs[h] + rb * 256 + (cb ^ ((rb & 7) << 4)));
                acc[0][nt] = __builtin_amdgcn_mfma_f32_16x16x32_f16(
                    __builtin_bit_cast(h8, af0), __builtin_bit_cast(h8, bf), acc[0][nt], 0, 0, 0);
                acc[1][nt] = __builtin_amdgcn_mfma_f32_16x16x32_f16(
                    __builtin_bit_cast(h8, af1), __builtin_bit_cast(h8, bf), acc[1][nt], 0, 0, 0);
            }
        }
    };

    // ---- stage half 0 ----
    A_dma(0);
    {
        float4 b0[8][2];
#pragma unroll
        for (int r = 0; r < 8; ++r) {
            int row = r * 16 + srow_off;
            const float4* src = (const float4*)(W + (size_t)(i0 + row) * TWO_D + (tid & 15) * 8);
            b0[r][0] = src[0]; b0[r][1] = src[1];
        }
#pragma unroll
        for (int r = 0; r < 8; ++r) {
            int row = r * 16 + srow_off;
            *(s8*)(Bs[0] + row * 256 + (scol ^ ((row & 7) << 4))) = pack8(b0[r][0], b0[r][1]);
        }
    }
    __syncthreads();                        // drains vmcnt(0)+lgkmcnt: h0 ready

    // ---- stage half 1 (overlapped with compute of half 0) ----
    A_dma(1);                               // fire-and-forget
    float4 b1[8][2];
#pragma unroll
    for (int r = 0; r < 8; ++r) {           // issue B h1 loads; consume later
        int row = r * 16 + srow_off;
        const float4* src = (const float4*)(W + (size_t)(i0 + row) * TWO_D + D + (tid & 15) * 8);
        b1[r][0] = src[0]; b1[r][1] = src[1];
    }
    compute_half(0);                        // MFMA on h0 while h1 in flight
#pragma unroll
    for (int r = 0; r < 8; ++r) {
        int row = r * 16 + srow_off;
        *(s8*)(Bs[1] + row * 256 + (scol ^ ((row & 7) << 4))) = pack8(b1[r][0], b1[r][1]);
    }
    __syncthreads();                        // h1 ready
    compute_half(1);

    // Epilogue: D layout col=lane&15, row=quad*4+r.
#pragma unroll
    for (int mt = 0; mt < 2; ++mt) {
#pragma unroll
        for (int nt = 0; nt < 8; ++nt) {
#pragma unroll
            for (int r = 0; r < 4; ++r) {
                int grow = row0 + w * 32 + mt * 16 + quad * 4 + r;
                if (grow < M)
                    wq_h[(size_t)grow * TWO_D + i0 + nt * 16 + l16] = f2h(acc[mt][nt][r]);
            }
        }
    }
}

// ---------------------------------------------------------------------------
// Kernel B: gather + score + softmax + weighted sum. One wave per row, 2
// rows/block. Gather staged via global_load_lds DMA: 16 instrs/wave, ZERO
// dest VGPRs (the r0-r3 register-staging fight is structurally eliminated).
// Per-wave private 16 KiB LDS region -> NO __syncthreads anywhere; the only
// sync is the wave's own vmcnt drain. 32 KiB/block -> 10 waves/CU; ~50 VGPR.
// LDS layout per wave: planeA [slot s=4p+g][256B v-half], planeB same for t.
// DMA instr p writes slots (p, g=0..3): lane(g,j) -> base + p*1024 + lane*16.
// Phases read base + p*1024 + lane*16 (contiguous per wave: conflict-free).
// Softmax order-invariant over slots => no edge-index remap needed.
// ---------------------------------------------------------------------------
__global__ __launch_bounds__(128) void attn_kernel(
    const unsigned short* __restrict__ ph, const int* __restrict__ ef,
    const unsigned short* __restrict__ wq_h, float* __restrict__ outp, int M)
{
    __shared__ char smem[2][16384];

    const int lane = threadIdx.x & 63;
    const int w    = threadIdx.x >> 6;
    const int n    = blockIdx.x * 2 + w;
    if (n >= M) return;

    const int g = lane >> 4;            // edge subgroup 0..3
    const int j = lane & 15;            // 16B column segment

    // wq for cols [j*8, j*8+8) of each half; issue early (hides under DMA)
    const unsigned short* wp = wq_h + (size_t)n * TWO_D + j * 8;
    s8 wqa = *(const s8*)(wp);
    s8 wqb = *(const s8*)(wp + D);

    int eidx = 0;
    if (lane < KNB) eidx = ef[n * KNB + lane];

    // ---- Phase 1: 16 DMA gathers (v-half -> planeA, t-half -> planeB) ----
    char* base = smem[w];
#pragma unroll
    for (int p = 0; p < 8; ++p) {
        int e = __shfl(eidx, 4 * p + g, 64);
        const char* rp = (const char*)ph + (size_t)e * 512 + j * 16;
        gl_lds16(rp,       base + p * 1024);          // planeA slot (p,g)
        gl_lds16(rp + 256, base + 8192 + p * 1024);   // planeB slot (p,g)
    }
    asm volatile("s_waitcnt vmcnt(0)" ::: "memory");  // own DMA drain (no barrier)
    __builtin_amdgcn_sched_barrier(0);

    // ---- Phase 2: partial dots from LDS (independent chains) ----
    float s[8];
#pragma unroll
    for (int p = 0; p < 8; ++p) {
        s8 v8 = *(const s8*)(base + p * 1024 + lane * 16);
        s8 t8 = *(const s8*)(base + 8192 + p * 1024 + lane * 16);
        float t = dot8(v8, wqa, 0.f);
        s[p] = dot8(t8, wqb, t);
    }

    // ---- Phase 3: 16-lane reduce trees, global max, exact softmax ----
#pragma unroll
    for (int p = 0; p < 8; ++p) {
#pragma unroll
        for (int off = 8; off; off >>= 1) s[p] += __shfl_xor(s[p], off, 64);
    }
    float m = -1e30f;
#pragma unroll
    for (int p = 0; p < 8; ++p) {
        float sb = __shfl_xor(s[p], 16, 64);
        float m2 = fmaxf(s[p], sb);
        float m3 = __shfl_xor(m2, 32, 64);
        m = fmaxf(m, fmaxf(m2, m3));
    }
    float e[8];
    float psum = 0.f;
#pragma unroll
    for (int p = 0; p < 8; ++p) {
        e[p] = __expf(s[p] - m);
        psum += e[p];
    }
    psum += __shfl_xor(psum, 16, 64);
    psum += __shfl_xor(psum, 32, 64);

    // ---- Phase 4: weighted sum from planeA; e[p] is own-slot weight ----
    float o[8] = {};
#pragma unroll
    for (int p = 0; p < 8; ++p) {
        s8 v8 = *(const s8*)(base + p * 1024 + lane * 16);
        v16u u; u.s = v8;
#pragma unroll
        for (int t = 0; t < 4; ++t) {
            o[2*t]   = fmaf(e[p], (float)u.h[t][0], o[2*t]);
            o[2*t+1] = fmaf(e[p], (float)u.h[t][1], o[2*t+1]);
        }
    }
#pragma unroll
    for (int t = 0; t < 8; ++t) {       // fold the 4 edge-groups
        o[t] += __shfl_xor(o[t], 16, 64);
        o[t] += __shfl_xor(o[t], 32, 64);
    }

    if (lane < 16) {                    // g==0: cols [j*8, j*8+8)
        float inv = 1.0f / psum;
        float* orow = outp + (size_t)n * D + j * 8;
        *(float4*)(orow)     = make_float4(o[0]*inv, o[1]*inv, o[2]*inv, o[3]*inv);
        *(float4*)(orow + 4) = make_float4(o[4]*inv, o[5]*inv, o[6]*inv, o[7]*inv);
    }
}

// ---------------------------------------------------------------------------
extern "C" void kernel_launch(void* const* d_in, const int* in_sizes, int n_in,
                              void* d_out, int out_size, void* d_ws, size_t ws_size,
                              hipStream_t stream)
{
    const float* v_fea = (const float*)d_in[0];
    const float* t_emb = (const float*)d_in[1];
    const int*   ef    = (const int*)d_in[2];
    const float* W     = (const float*)d_in[3];
    float* outp = (float*)d_out;

    const int M = in_sizes[0] / D;                  // 50000
    // ws layout: wq_h (fp16, 25.6 MB) | ph (fp16 packed v|t, 25.6 MB)
    char* ws = (char*)d_ws;
    unsigned short* wq_h = (unsigned short*)ws;
    unsigned short* ph   = (unsigned short*)(ws + (size_t)M * TWO_D * 2);

    const int total = M * 16;
    cast_kernel<<<(total + 255) / 256, 256, 0, stream>>>(v_fea, t_emb, ph, total);

    dim3 gg((M + BM - 1) / BM, TWO_D / BN);
    gemm_wq_mfma<<<gg, 256, 0, stream>>>(ph, W, wq_h, M);
    attn_kernel<<<(M + 1) / 2, 128, 0, stream>>>(ph, ef, wq_h, outp, M);
}

// Round 5
// 222.933 us; speedup vs baseline: 1.0792x; 1.0792x over previous
//
#include <hip/hip_runtime.h>
#include <hip/hip_bf16.h>

// Problem constants: N=50000, K=32, D=128.
#define D     128
#define TWO_D 256
#define KNB   32

typedef __attribute__((ext_vector_type(8))) short    s8;   // 8 x 16-bit (4 VGPR)
typedef __attribute__((ext_vector_type(8))) _Float16 h8;   // mfma operand view
typedef __attribute__((ext_vector_type(2))) _Float16 h2v;
typedef __attribute__((ext_vector_type(4))) float    f4;   // MFMA acc

__device__ inline unsigned short f2h(float f) {
    return __builtin_bit_cast(unsigned short, (_Float16)f);
}
__device__ inline float h2f(unsigned short u) {
    return (float)__builtin_bit_cast(_Float16, u);
}

union v16u { s8 s; h2v h[4]; };

// 8-elem fp16 dot with f32 accumulate; v_dot2_f32_f16 when available.
__device__ inline float dot8(s8 x, s8 w, float acc) {
#if __has_builtin(__builtin_amdgcn_fdot2)
    v16u ux, uw; ux.s = x; uw.s = w;
#pragma unroll
    for (int j = 0; j < 4; ++j)
        acc = __builtin_amdgcn_fdot2(ux.h[j], uw.h[j], acc, false);
#else
#pragma unroll
    for (int j = 0; j < 8; ++j)
        acc = fmaf(h2f((unsigned short)x[j]), h2f((unsigned short)w[j]), acc);
#endif
    return acc;
}

// Direct global->LDS DMA, 16 B per lane. LDS dest = base + lane*16 (linear);
// global src is per-lane. Zero VGPR destination cost; tracked by vmcnt.
__device__ inline void gl_lds16(const void* g, void* l) {
    __builtin_amdgcn_global_load_lds(
        (const __attribute__((address_space(1))) void*)g,
        (__attribute__((address_space(3))) void*)l, 16, 0, 0);
}

__device__ inline s8 pack8(float4 x, float4 y) {
    s8 q;
    q[0]=(short)f2h(x.x); q[1]=(short)f2h(x.y); q[2]=(short)f2h(x.z); q[3]=(short)f2h(x.w);
    q[4]=(short)f2h(y.x); q[5]=(short)f2h(y.y); q[6]=(short)f2h(y.z); q[7]=(short)f2h(y.w);
    return q;
}

// ---------------------------------------------------------------------------
// Kernel A (FUSED cast+gemm): wq = [v|t] @ W^T via fp16 MFMA, and ph (packed
// fp16 [v|t], 512 B/row) written as a side output by blockIdx.y==0 blocks.
// A-tiles: f32 source loads + inline cvt (the old standalone cast kernel is
// deleted -- saves one launch + a 51 MB ph re-read).
// 128x128 tile, BK=32, 4 waves; 28 KiB LDS -> good occupancy.
// ---------------------------------------------------------------------------
#define BM 128
#define BN 128
#define BK 32
#define LDT 56   // row stride (elems): 112 B = 16B-aligned; 2-way banks only

__global__ __launch_bounds__(256) void gemm_cast_wq(
    const float* __restrict__ v_fea, const float* __restrict__ t_emb,
    const float* __restrict__ W, unsigned short* __restrict__ wq_h,
    unsigned short* __restrict__ ph, int M)
{
    __shared__ unsigned short As[BM][LDT];
    __shared__ unsigned short Bs[BN][LDT];

    const int tid  = threadIdx.x;
    const int w    = tid >> 6;
    const int lane = tid & 63;
    const int quad = lane >> 4;
    const int l16  = lane & 15;
    const int row0 = blockIdx.x * BM;
    const int i0   = blockIdx.y * BN;
    const bool wr_ph = (blockIdx.y == 0);

    f4 acc[2][8] = {};

    const int srow = tid >> 1;          // 0..127 (tile row this thread stages)
    const int seg  = tid & 1;           // 16-elem k-segment
    const int grow_s = row0 + srow;
    int ga = grow_s; if (ga >= M) ga = M - 1;        // clamp (stores guarded)

    for (int kt = 0; kt < TWO_D; kt += BK) {
        // A: f32 source, inline cvt. 16 floats/thread.
        const float* srcA = (kt < D) ? v_fea : t_emb;
        const int kb = (kt & (D - 1)) + seg * 16;
        const float* pa = srcA + (size_t)ga * D + kb;
        float4 a0 = *(const float4*)(pa);
        float4 a1 = *(const float4*)(pa + 4);
        float4 a2 = *(const float4*)(pa + 8);
        float4 a3 = *(const float4*)(pa + 12);
        // B: W f32 rows, inline cvt. 16 floats/thread.
        const float* pb = W + (size_t)(i0 + srow) * TWO_D + kt + seg * 16;
        float4 b0 = *(const float4*)(pb);
        float4 b1 = *(const float4*)(pb + 4);
        float4 b2 = *(const float4*)(pb + 8);
        float4 b3 = *(const float4*)(pb + 12);

        s8 A0 = pack8(a0, a1), A1 = pack8(a2, a3);
        // side output: packed fp16 [v|t] row for the attn gather table
        if (wr_ph && grow_s < M) {
            *(s8*)(ph + (size_t)grow_s * TWO_D + kt + seg * 16)     = A0;
            *(s8*)(ph + (size_t)grow_s * TWO_D + kt + seg * 16 + 8) = A1;
        }

        __syncthreads();   // prior iter's frag reads done before overwrite
        *(s8*)&As[srow][seg * 16]     = A0;
        *(s8*)&As[srow][seg * 16 + 8] = A1;
        *(s8*)&Bs[srow][seg * 16]     = pack8(b0, b1);
        *(s8*)&Bs[srow][seg * 16 + 8] = pack8(b2, b3);
        __syncthreads();

        // A frag: m = lane&15 (+tile), k = quad*8+j; B frag: n = lane&15 (+tile).
        s8 af0 = *(const s8*)&As[w * 32 + l16][quad * 8];
        s8 af1 = *(const s8*)&As[w * 32 + 16 + l16][quad * 8];
#pragma unroll
        for (int nt = 0; nt < 8; ++nt) {
            s8 bf = *(const s8*)&Bs[nt * 16 + l16][quad * 8];
            acc[0][nt] = __builtin_amdgcn_mfma_f32_16x16x32_f16(
                __builtin_bit_cast(h8, af0), __builtin_bit_cast(h8, bf), acc[0][nt], 0, 0, 0);
            acc[1][nt] = __builtin_amdgcn_mfma_f32_16x16x32_f16(
                __builtin_bit_cast(h8, af1), __builtin_bit_cast(h8, bf), acc[1][nt], 0, 0, 0);
        }
    }

    // Epilogue: D layout col=lane&15, row=quad*4+r.
#pragma unroll
    for (int mt = 0; mt < 2; ++mt) {
#pragma unroll
        for (int nt = 0; nt < 8; ++nt) {
#pragma unroll
            for (int r = 0; r < 4; ++r) {
                int grow = row0 + w * 32 + mt * 16 + quad * 4 + r;
                if (grow < M)
                    wq_h[(size_t)grow * TWO_D + i0 + nt * 16 + l16] = f2h(acc[mt][nt][r]);
            }
        }
    }
}

// ---------------------------------------------------------------------------
// Kernel B: gather + score + softmax + weighted sum. One wave per row, 4
// rows/block. Occupancy-first restructure of r4:
//   - Only the v-half (read TWICE: score + weighted sum) is LDS-staged via
//     global_load_lds DMA: 8 KiB/wave, 32 KiB per 4-wave block -> 5 blocks =
//     20 waves/CU (r4: 32 KiB per 2-wave block -> 6.6 waves/CU measured).
//   - The t-half (read ONCE, score only) streams through 32 VGPRs.
//   - Per-wave private LDS region -> NO __syncthreads; single vmcnt(0) drain.
//   - waves_per_eu(5,6): ~85 VGPR live; stops the 48-VGPR heuristic clamp.
// Lane (g=lane>>4, j=lane&15) covers elems [j*8, j*8+8) of edge 4p+g.
// ---------------------------------------------------------------------------
__global__ __attribute__((amdgpu_waves_per_eu(5, 6))) __launch_bounds__(256)
void attn_kernel(
    const unsigned short* __restrict__ ph, const int* __restrict__ ef,
    const unsigned short* __restrict__ wq_h, float* __restrict__ outp, int M)
{
    __shared__ char smem[4][8192];

    const int lane = threadIdx.x & 63;
    const int w    = threadIdx.x >> 6;
    const int n    = blockIdx.x * 4 + w;
    if (n >= M) return;

    const int g = lane >> 4;            // edge subgroup 0..3
    const int j = lane & 15;            // 8-elem column segment

    // wq for elems [j*8,+8) of each half; issued early (hides under gathers)
    const unsigned short* wp = wq_h + (size_t)n * TWO_D + j * 8;
    s8 wqa = *(const s8*)(wp);
    s8 wqb = *(const s8*)(wp + D);

    int eidx = 0;
    if (lane < KNB) eidx = ef[n * KNB + lane];

    // ---- Phase 1: v-half -> LDS DMA (slot p), t-half -> regs ----
    char* base = smem[w];
    s8 t8[8];
#pragma unroll
    for (int p = 0; p < 8; ++p) {
        int e = __shfl(eidx, 4 * p + g, 64);
        const char* rp = (const char*)ph + (size_t)e * 512 + j * 16;
        gl_lds16(rp, base + p * 1024);          // v-half: slot (p, g), lane*16
        t8[p] = *(const s8*)(rp + 256);         // t-half: kept in registers
    }
    asm volatile("s_waitcnt vmcnt(0)" ::: "memory");  // own drain (no barrier)
    __builtin_amdgcn_sched_barrier(0);

    // ---- Phase 2: partial dots (independent chains; v from LDS, t regs) ----
    float s[8];
#pragma unroll
    for (int p = 0; p < 8; ++p) {
        s8 v8 = *(const s8*)(base + p * 1024 + lane * 16);
        float t = dot8(v8, wqa, 0.f);
        s[p] = dot8(t8[p], wqb, t);
    }

    // ---- Phase 3: 16-lane reduce trees, global max, exact softmax ----
#pragma unroll
    for (int p = 0; p < 8; ++p) {
#pragma unroll
        for (int off = 8; off; off >>= 1) s[p] += __shfl_xor(s[p], off, 64);
    }
    float m = -1e30f;
#pragma unroll
    for (int p = 0; p < 8; ++p) {
        float sb = __shfl_xor(s[p], 16, 64);
        float m2 = fmaxf(s[p], sb);
        float m3 = __shfl_xor(m2, 32, 64);
        m = fmaxf(m, fmaxf(m2, m3));
    }
    float e[8];
    float psum = 0.f;
#pragma unroll
    for (int p = 0; p < 8; ++p) {
        e[p] = __expf(s[p] - m);
        psum += e[p];
    }
    psum += __shfl_xor(psum, 16, 64);
    psum += __shfl_xor(psum, 32, 64);

    // ---- Phase 4: weighted sum from LDS v-slots; e[p] is own-slot weight ----
    float o[8] = {};
#pragma unroll
    for (int p = 0; p < 8; ++p) {
        s8 v8 = *(const s8*)(base + p * 1024 + lane * 16);
        v16u u; u.s = v8;
#pragma unroll
        for (int t = 0; t < 4; ++t) {
            o[2*t]   = fmaf(e[p], (float)u.h[t][0], o[2*t]);
            o[2*t+1] = fmaf(e[p], (float)u.h[t][1], o[2*t+1]);
        }
    }
#pragma unroll
    for (int t = 0; t < 8; ++t) {       // fold the 4 edge-groups
        o[t] += __shfl_xor(o[t], 16, 64);
        o[t] += __shfl_xor(o[t], 32, 64);
    }

    if (lane < 16) {                    // g==0: elems [j*8, j*8+8)
        float inv = 1.0f / psum;
        float* orow = outp + (size_t)n * D + j * 8;
        *(float4*)(orow)     = make_float4(o[0]*inv, o[1]*inv, o[2]*inv, o[3]*inv);
        *(float4*)(orow + 4) = make_float4(o[4]*inv, o[5]*inv, o[6]*inv, o[7]*inv);
    }
}

// ---------------------------------------------------------------------------
extern "C" void kernel_launch(void* const* d_in, const int* in_sizes, int n_in,
                              void* d_out, int out_size, void* d_ws, size_t ws_size,
                              hipStream_t stream)
{
    const float* v_fea = (const float*)d_in[0];
    const float* t_emb = (const float*)d_in[1];
    const int*   ef    = (const int*)d_in[2];
    const float* W     = (const float*)d_in[3];
    float* outp = (float*)d_out;

    const int M = in_sizes[0] / D;                  // 50000
    // ws layout: wq_h (fp16, 25.6 MB) | ph (fp16 packed v|t, 25.6 MB)
    char* ws = (char*)d_ws;
    unsigned short* wq_h = (unsigned short*)ws;
    unsigned short* ph   = (unsigned short*)(ws + (size_t)M * TWO_D * 2);

    dim3 gg((M + BM - 1) / BM, TWO_D / BN);
    gemm_cast_wq<<<gg, 256, 0, stream>>>(v_fea, t_emb, W, wq_h, ph, M);
    attn_kernel<<<(M + 3) / 4, 256, 0, stream>>>(ph, ef, wq_h, outp, M);
}